// Round 3
// baseline (977.669 us; speedup 1.0000x reference)
//
#include <hip/hip_runtime.h>

#define IN_F 4096
#define OUT_F 11008
#define BM 128
#define BN 128
#define BK 64

typedef __attribute__((ext_vector_type(8))) short bf16x8;   // 8 bf16 (4 VGPR) MFMA operand
typedef __attribute__((ext_vector_type(4))) float f32x4;
typedef __attribute__((ext_vector_type(4))) unsigned short us4;
typedef __attribute__((ext_vector_type(8))) unsigned short us8;

__device__ __forceinline__ unsigned short f2bf(float f) {
  unsigned int u = __float_as_uint(f);
  u += 0x7FFFu + ((u >> 16) & 1u);   // RNE
  return (unsigned short)(u >> 16);
}

// ---------------- prepass 1: X fp32 -> bf16 ----------------
__global__ __launch_bounds__(256) void cvt_x(const float* __restrict__ X,
                                             unsigned short* __restrict__ Xb, int n8) {
  for (int i = blockIdx.x * blockDim.x + threadIdx.x; i < n8;
       i += gridDim.x * blockDim.x) {
    const float4 a = reinterpret_cast<const float4*>(X)[2 * i];
    const float4 b = reinterpret_cast<const float4*>(X)[2 * i + 1];
    us8 h;
    h[0] = f2bf(a.x); h[1] = f2bf(a.y); h[2] = f2bf(a.z); h[3] = f2bf(a.w);
    h[4] = f2bf(b.x); h[5] = f2bf(b.y); h[6] = f2bf(b.z); h[7] = f2bf(b.w);
    reinterpret_cast<us8*>(Xb)[i] = h;
  }
}

// ---------------- prepass 2: W nf4 packed -> bf16 (dequant once) ----------------
__global__ __launch_bounds__(256) void dequant_w(const int* __restrict__ Wp,
                                                 const float* __restrict__ Amax,
                                                 unsigned short* __restrict__ Wb, int n4) {
  __shared__ float lutS[16];
  if (threadIdx.x < 16) {
    const float lut[16] = {-1.0f, -0.6961928009986877f, -0.5250730514526367f,
        -0.39491719007492065f, -0.28444138169288635f, -0.18477343022823334f,
        -0.08820830285549164f, 0.0f, 0.07107656449079514f, 0.14263366162776947f,
        0.22430233657360077f, 0.3203405737876892f, 0.4407068192958832f,
        0.5905631184577942f, 0.796090841293335f, 1.0f};
    lutS[threadIdx.x] = lut[threadIdx.x];
  }
  __syncthreads();
  for (int i = blockIdx.x * blockDim.x + threadIdx.x; i < n4;
       i += gridDim.x * blockDim.x) {
    const int j = i * 4;              // first int32 index (4 int32 = 8 weights)
    const int row = j >> 11;          // / (IN_F/2)
    const int coli = j & 2047;
    const float am = Amax[row * (IN_F / 64) + (coli >> 5)];  // 4 int32 never cross a 64-w block
    const int4 pk = reinterpret_cast<const int4*>(Wp)[i];
    us8 h; int c;
    c = pk.x & 255; h[0] = f2bf(lutS[c & 15] * am); h[1] = f2bf(lutS[c >> 4] * am);
    c = pk.y & 255; h[2] = f2bf(lutS[c & 15] * am); h[3] = f2bf(lutS[c >> 4] * am);
    c = pk.z & 255; h[4] = f2bf(lutS[c & 15] * am); h[5] = f2bf(lutS[c >> 4] * am);
    c = pk.w & 255; h[6] = f2bf(lutS[c & 15] * am); h[7] = f2bf(lutS[c >> 4] * am);
    reinterpret_cast<us8*>(Wb)[i] = h;
  }
}

// ---------------- main GEMM: m97 structure + XOR-swizzled LDS + m-fast order ----------------
__global__ __launch_bounds__(256, 4) void gemm_bt(
    const unsigned short* __restrict__ A,   // (M, K) bf16
    const unsigned short* __restrict__ B,   // (N, K) bf16  (B^T layout)
    const float* __restrict__ Bias, float* __restrict__ Out, int M) {
  __shared__ unsigned short As[BM * BK];   // 16 KiB, rows of 128B, XOR-swizzled content
  __shared__ unsigned short Bs[BN * BK];   // 16 KiB

  const int t = threadIdx.x;
  const int l = t & 63;
  const int wid = t >> 6;

  // XCD-chunked, column-major (m-fast): B-panel L2-resident per XCD, A L3-shared.
  const int Mb = M / BM;                        // 64
  const int Nb = OUT_F / BN;                    // 86
  const int cpx = (Mb * Nb) >> 3;               // 688
  const int bid = (blockIdx.x & 7) * cpx + (blockIdx.x >> 3);
  const int m0 = (bid % Mb) * BM;
  const int n0 = (bid / Mb) * BN;

  const int wm = (wid >> 1) * 64;
  const int wn = (wid & 1) * 64;

  // staging: wave writes 1 KiB = 8 rows x 128B, LDS dest LINEAR (HW: base + lane*16).
  // Pre-swizzled global source: lane l covers tile row (l>>3), source chunk (l&7)^(l>>3)
  // so that LDS[row][s] holds global chunk s^(row&7)  (involution, read applies same XOR).
  const int srow = wid * 8 + (l >> 3);
  const int schunk = ((l & 7) ^ (l >> 3)) * 8;          // bf16 units within 64-col K-slice
  const unsigned short* gA = A + (size_t)(m0 + srow) * IN_F + schunk;
  const unsigned short* gB = B + (size_t)(n0 + srow) * IN_F + schunk;

  f32x4 acc[4][4];
#pragma unroll
  for (int i = 0; i < 4; ++i)
#pragma unroll
    for (int j = 0; j < 4; ++j) acc[i][j] = {0.f, 0.f, 0.f, 0.f};

  for (int k0 = 0; k0 < IN_F; k0 += BK) {
#pragma unroll
    for (int p = 0; p < 4; ++p) {
      __builtin_amdgcn_global_load_lds(
          (const __attribute__((address_space(1))) void*)(gA + (size_t)p * 32 * IN_F + k0),
          (__attribute__((address_space(3))) void*)(As + (p * 32 + wid * 8) * 64),
          16, 0, 0);
      __builtin_amdgcn_global_load_lds(
          (const __attribute__((address_space(1))) void*)(gB + (size_t)p * 32 * IN_F + k0),
          (__attribute__((address_space(3))) void*)(Bs + (p * 32 + wid * 8) * 64),
          16, 0, 0);
    }
    __syncthreads();

#pragma unroll
    for (int kk = 0; kk < BK; kk += 32) {
      bf16x8 af[4], bfv[4];
      const int kb = (kk + ((l >> 4) << 3)) * 2;   // byte col (16B-aligned chunk)
#pragma unroll
      for (int i = 0; i < 4; ++i) {
        const int row = wm + i * 16 + (l & 15);
        af[i] = *reinterpret_cast<const bf16x8*>(
            reinterpret_cast<const char*>(As) + row * 128 + (kb ^ ((row & 7) << 4)));
      }
#pragma unroll
      for (int j = 0; j < 4; ++j) {
        const int row = wn + j * 16 + (l & 15);
        bfv[j] = *reinterpret_cast<const bf16x8*>(
            reinterpret_cast<const char*>(Bs) + row * 128 + (kb ^ ((row & 7) << 4)));
      }
#pragma unroll
      for (int i = 0; i < 4; ++i)
#pragma unroll
        for (int j = 0; j < 4; ++j)
          acc[i][j] = __builtin_amdgcn_mfma_f32_16x16x32_bf16(af[i], bfv[j], acc[i][j], 0, 0, 0);
    }
    __syncthreads();
  }

  // epilogue: C = acc + bias   (C/D map: col = l&15, row = (l>>4)*4 + reg)
  const int crow0 = m0 + wm + ((l >> 4) << 2);
  const int ccol0 = n0 + wn + (l & 15);
#pragma unroll
  for (int j = 0; j < 4; ++j) {
    const float bv = Bias[ccol0 + j * 16];
#pragma unroll
    for (int i = 0; i < 4; ++i)
#pragma unroll
      for (int rg = 0; rg < 4; ++rg)
        Out[(size_t)(crow0 + i * 16 + rg) * OUT_F + ccol0 + j * 16] = acc[i][j][rg] + bv;
  }
}

// ---------------- fallback: fused kernel (if ws too small) ----------------
__global__ __launch_bounds__(256, 2) void nf4_gemm_fused(
    const float* __restrict__ X, const int* __restrict__ Wp,
    const float* __restrict__ Amax, const float* __restrict__ Bias,
    float* __restrict__ Out, int M) {
  __shared__ unsigned short As[BM * BK];
  __shared__ unsigned short Bs[BN * BK];
  __shared__ float lutS[16];

  const int t = threadIdx.x;
  const int l = t & 63;
  const int wid = t >> 6;

  if (t < 16) {
    const float lut[16] = {-1.0f, -0.6961928009986877f, -0.5250730514526367f,
        -0.39491719007492065f, -0.28444138169288635f, -0.18477343022823334f,
        -0.08820830285549164f, 0.0f, 0.07107656449079514f, 0.14263366162776947f,
        0.22430233657360077f, 0.3203405737876892f, 0.4407068192958832f,
        0.5905631184577942f, 0.796090841293335f, 1.0f};
    lutS[t] = lut[t];
  }

  const int ntile = OUT_F / BN;
  const int m0 = (blockIdx.x / ntile) * BM;
  const int n0 = (blockIdx.x % ntile) * BN;

  const int ar = t >> 4;
  const int ac4 = t & 15;
  const int br = t >> 3;
  const int bg = t & 7;
  const int wm = (wid >> 1) * 64;
  const int wn = (wid & 1) * 64;

  f32x4 acc[4][4];
#pragma unroll
  for (int i = 0; i < 4; ++i)
#pragma unroll
    for (int j = 0; j < 4; ++j) acc[i][j] = {0.f, 0.f, 0.f, 0.f};

  __syncthreads();

  for (int k0 = 0; k0 < IN_F; k0 += BK) {
#pragma unroll
    for (int p = 0; p < 8; ++p) {
      const int r = p * 16 + ar;
      const float4 v = *reinterpret_cast<const float4*>(
          X + (size_t)(m0 + r) * IN_F + k0 + ac4 * 4);
      us4 h;
      h[0] = f2bf(v.x); h[1] = f2bf(v.y); h[2] = f2bf(v.z); h[3] = f2bf(v.w);
      const int byte = r * 128 + ((ac4 * 8) ^ ((r & 7) << 4));
      *reinterpret_cast<us4*>(reinterpret_cast<char*>(As) + byte) = h;
    }
#pragma unroll
    for (int p = 0; p < 4; ++p) {
      const int r = p * 32 + br;
      const float amv = Amax[(size_t)(n0 + r) * (IN_F / 64) + (k0 >> 6)];
      const int4 pk = *reinterpret_cast<const int4*>(
          Wp + (size_t)(n0 + r) * (IN_F / 2) + (k0 >> 1) + bg * 4);
      us8 h;
      {
        int c;
        c = pk.x & 255; h[0] = f2bf(lutS[c & 15] * amv); h[1] = f2bf(lutS[c >> 4] * amv);
        c = pk.y & 255; h[2] = f2bf(lutS[c & 15] * amv); h[3] = f2bf(lutS[c >> 4] * amv);
        c = pk.z & 255; h[4] = f2bf(lutS[c & 15] * amv); h[5] = f2bf(lutS[c >> 4] * amv);
        c = pk.w & 255; h[6] = f2bf(lutS[c & 15] * amv); h[7] = f2bf(lutS[c >> 4] * amv);
      }
      const int byte = r * 128 + ((bg * 16) ^ ((r & 7) << 4));
      *reinterpret_cast<us8*>(reinterpret_cast<char*>(Bs) + byte) = h;
    }
    __syncthreads();

#pragma unroll
    for (int kk = 0; kk < BK; kk += 32) {
      bf16x8 af[4], bfv[4];
      const int kb = (kk + ((l >> 4) << 3)) * 2;
#pragma unroll
      for (int i = 0; i < 4; ++i) {
        const int row = wm + i * 16 + (l & 15);
        af[i] = *reinterpret_cast<const bf16x8*>(
            reinterpret_cast<const char*>(As) + row * 128 + (kb ^ ((row & 7) << 4)));
      }
#pragma unroll
      for (int j = 0; j < 4; ++j) {
        const int row = wn + j * 16 + (l & 15);
        bfv[j] = *reinterpret_cast<const bf16x8*>(
            reinterpret_cast<const char*>(Bs) + row * 128 + (kb ^ ((row & 7) << 4)));
      }
#pragma unroll
      for (int i = 0; i < 4; ++i)
#pragma unroll
        for (int j = 0; j < 4; ++j)
          acc[i][j] = __builtin_amdgcn_mfma_f32_16x16x32_bf16(af[i], bfv[j], acc[i][j], 0, 0, 0);
    }
    __syncthreads();
  }

  const int crow0 = m0 + wm + ((l >> 4) << 2);
  const int ccol0 = n0 + wn + (l & 15);
#pragma unroll
  for (int j = 0; j < 4; ++j) {
    const float bv = Bias[ccol0 + j * 16];
#pragma unroll
    for (int i = 0; i < 4; ++i)
#pragma unroll
      for (int rg = 0; rg < 4; ++rg)
        Out[(size_t)(crow0 + i * 16 + rg) * OUT_F + ccol0 + j * 16] = acc[i][j][rg] + bv;
  }
}

extern "C" void kernel_launch(void* const* d_in, const int* in_sizes, int n_in,
                              void* d_out, int out_size, void* d_ws, size_t ws_size,
                              hipStream_t stream) {
  const float* X = (const float*)d_in[0];
  const int* Wp = (const int*)d_in[1];
  const float* Amax = (const float*)d_in[2];
  const float* Bias = (const float*)d_in[3];
  float* Out = (float*)d_out;

  const int M = in_sizes[0] / IN_F;                       // 8192
  const size_t needX = (size_t)M * IN_F * 2;              // 67 MB
  const size_t needW = (size_t)OUT_F * IN_F * 2;          // 90 MB
  const int grid = (M / BM) * (OUT_F / BN);               // 5504

  if (ws_size >= needX + needW && (grid & 7) == 0) {
    unsigned short* Xb = (unsigned short*)d_ws;
    unsigned short* Wb = Xb + (size_t)M * IN_F;
    cvt_x<<<2048, 256, 0, stream>>>(X, Xb, M * (IN_F / 8));
    dequant_w<<<2048, 256, 0, stream>>>(Wp, Amax, Wb, OUT_F * (IN_F / 8));
    gemm_bt<<<grid, 256, 0, stream>>>(Xb, Wb, Bias, Out, M);
  } else {
    nf4_gemm_fused<<<grid, 256, 0, stream>>>(X, Wp, Amax, Bias, Out, M);
  }
}

// Round 4
// 896.160 us; speedup vs baseline: 1.0910x; 1.0910x over previous
//
#include <hip/hip_runtime.h>

#define IN_F 4096
#define OUT_F 11008

typedef __attribute__((ext_vector_type(8))) short bf16x8;   // 8 bf16 (4 VGPR) MFMA operand
typedef __attribute__((ext_vector_type(4))) float f32x4;
typedef __attribute__((ext_vector_type(4))) unsigned short us4;
typedef __attribute__((ext_vector_type(8))) unsigned short us8;

__device__ __forceinline__ unsigned short f2bf(float f) {
  unsigned int u = __float_as_uint(f);
  u += 0x7FFFu + ((u >> 16) & 1u);   // RNE
  return (unsigned short)(u >> 16);
}

// ---------------- prepass 1: X fp32 -> bf16 ----------------
__global__ __launch_bounds__(256) void cvt_x(const float* __restrict__ X,
                                             unsigned short* __restrict__ Xb, int n8) {
  for (int i = blockIdx.x * blockDim.x + threadIdx.x; i < n8;
       i += gridDim.x * blockDim.x) {
    const float4 a = reinterpret_cast<const float4*>(X)[2 * i];
    const float4 b = reinterpret_cast<const float4*>(X)[2 * i + 1];
    us8 h;
    h[0] = f2bf(a.x); h[1] = f2bf(a.y); h[2] = f2bf(a.z); h[3] = f2bf(a.w);
    h[4] = f2bf(b.x); h[5] = f2bf(b.y); h[6] = f2bf(b.z); h[7] = f2bf(b.w);
    reinterpret_cast<us8*>(Xb)[i] = h;
  }
}

// ---------------- prepass 2: W nf4 packed -> bf16 (dequant once) ----------------
__global__ __launch_bounds__(256) void dequant_w(const int* __restrict__ Wp,
                                                 const float* __restrict__ Amax,
                                                 unsigned short* __restrict__ Wb, int n4) {
  __shared__ float lutS[16];
  if (threadIdx.x < 16) {
    const float lut[16] = {-1.0f, -0.6961928009986877f, -0.5250730514526367f,
        -0.39491719007492065f, -0.28444138169288635f, -0.18477343022823334f,
        -0.08820830285549164f, 0.0f, 0.07107656449079514f, 0.14263366162776947f,
        0.22430233657360077f, 0.3203405737876892f, 0.4407068192958832f,
        0.5905631184577942f, 0.796090841293335f, 1.0f};
    lutS[threadIdx.x] = lut[threadIdx.x];
  }
  __syncthreads();
  for (int i = blockIdx.x * blockDim.x + threadIdx.x; i < n4;
       i += gridDim.x * blockDim.x) {
    const int j = i * 4;
    const int row = j >> 11;
    const int coli = j & 2047;
    const float am = Amax[row * (IN_F / 64) + (coli >> 5)];
    const int4 pk = reinterpret_cast<const int4*>(Wp)[i];
    us8 h; int c;
    c = pk.x & 255; h[0] = f2bf(lutS[c & 15] * am); h[1] = f2bf(lutS[c >> 4] * am);
    c = pk.y & 255; h[2] = f2bf(lutS[c & 15] * am); h[3] = f2bf(lutS[c >> 4] * am);
    c = pk.z & 255; h[4] = f2bf(lutS[c & 15] * am); h[5] = f2bf(lutS[c >> 4] * am);
    c = pk.w & 255; h[6] = f2bf(lutS[c & 15] * am); h[7] = f2bf(lutS[c >> 4] * am);
    reinterpret_cast<us8*>(Wb)[i] = h;
  }
}

// ---------------- main GEMM: 256x256 tile, BK=32 ring-of-4, counted vmcnt ----------------
#define MF(a, b, c) __builtin_amdgcn_mfma_f32_16x16x32_bf16(a, b, c, 0, 0, 0)
#define GLDS(src, dst) __builtin_amdgcn_global_load_lds( \
    (const __attribute__((address_space(1))) void*)(src), \
    (__attribute__((address_space(3))) void*)(dst), 16, 0, 0)
#define FENCE asm volatile("" ::: "memory")
#define BAR do { FENCE; __builtin_amdgcn_s_barrier(); FENCE; } while (0)
#define VM8 asm volatile("s_waitcnt vmcnt(8)" ::: "memory")
#define VM4 asm volatile("s_waitcnt vmcnt(4)" ::: "memory")
#define VM0 asm volatile("s_waitcnt vmcnt(0)" ::: "memory")
#define VMN do {} while (0)

__global__ __launch_bounds__(512, 2) void gemm256(
    const unsigned short* __restrict__ A,   // (M, K) bf16
    const unsigned short* __restrict__ B,   // (N, K) bf16
    const float* __restrict__ Bias, float* __restrict__ Out, int M) {
  extern __shared__ unsigned short sm[];    // 128 KiB: 4 A-slots + 4 B-slots (16 KiB each)
  unsigned short* LA = sm;
  unsigned short* LB = sm + 32768;

  const int tid = threadIdx.x;
  const int l = tid & 63;
  const int wid = tid >> 6;

  const int Mb = M / 256;                   // 32
  const int Nb = OUT_F / 256;               // 43
  const int cpx = (Mb * Nb) >> 3;           // 172
  const int bid = (blockIdx.x & 7) * cpx + (blockIdx.x >> 3);
  const int m0 = (bid % Mb) * 256;
  const int n0 = (bid / Mb) * 256;

  // --- ds_read lane constants (paired-row layout: phys row = 2 logical rows, 128 B) ---
  // logical (R, kchunk) stored at phys (R>>1, ((R&1)*4 + kchunk) ^ (physrow&7))
  const int rh = (l & 15) >> 1;
  const int cph = (((l & 1) << 2) + (l >> 4)) ^ rh;       // phys 16B chunk, lane const
  const int aoff = (((wid >> 2) * 64) + rh) * 64 + cph * 8;   // elements
  const int boff = (((wid & 3) * 32) + rh) * 64 + cph * 8;

  // --- stage lane constants (LDS dest linear: wave base + lane*16B) ---
  const int cc = (l & 7) ^ (l >> 3);            // content chunk at this lane's dest
  const int R0 = 2 * (wid * 16 + (l >> 3)) + (cc >> 2);   // q=0 logical row within tile
  const long chb = (long)(cc & 3) * 16;                    // source k-chunk bytes
  const char* pA0 = (const char*)A + ((size_t)(m0 + R0) * IN_F) * 2 + chb;
  const char* pA1 = (const char*)A + ((size_t)(m0 + R0 + 16) * IN_F) * 2 + chb;
  const char* pB0 = (const char*)B + ((size_t)(n0 + R0) * IN_F) * 2 + chb;
  const char* pB1 = (const char*)B + ((size_t)(n0 + R0 + 16) * IN_F) * 2 + chb;
  const int dq0 = wid * 1024;                  // elements within slot
  const int dq1 = wid * 1024 + 512;

#define STAGE_A(tt) do { const int s_ = ((tt) & 3) * 8192; const size_t ko_ = (size_t)(tt) * 64; \
    GLDS(pA0 + ko_, LA + s_ + dq0); GLDS(pA1 + ko_, LA + s_ + dq1); } while (0)
#define STAGE_B(tt) do { const int s_ = ((tt) & 3) * 8192; const size_t ko_ = (size_t)(tt) * 64; \
    GLDS(pB0 + ko_, LB + s_ + dq0); GLDS(pB1 + ko_, LB + s_ + dq1); } while (0)

  f32x4 acc[8][4];
#pragma unroll
  for (int i = 0; i < 8; ++i)
#pragma unroll
    for (int j = 0; j < 4; ++j) acc[i][j] = {0.f, 0.f, 0.f, 0.f};

  // prologue: stage tiles 0,1,2; ensure tile 0 landed (8 = tiles 1,2 still in flight)
  STAGE_A(0); STAGE_B(0); STAGE_A(1); STAGE_B(1); STAGE_A(2); STAGE_B(2);
  VM8;
  __builtin_amdgcn_s_barrier();
  FENCE;

#define TILE(t, STG, VMW) do { \
  const int sb = ((t) & 3) * 8192; \
  bf16x8 a0, a1, a2, a3, b0, b1, b2, b3; \
  a0 = *(const bf16x8*)(LA + sb + aoff); \
  a1 = *(const bf16x8*)(LA + sb + aoff + 512); \
  a2 = *(const bf16x8*)(LA + sb + aoff + 1024); \
  a3 = *(const bf16x8*)(LA + sb + aoff + 1536); \
  b0 = *(const bf16x8*)(LB + sb + boff); \
  b1 = *(const bf16x8*)(LB + sb + boff + 512); \
  b2 = *(const bf16x8*)(LB + sb + boff + 1024); \
  b3 = *(const bf16x8*)(LB + sb + boff + 1536); \
  if (STG) STAGE_A((t) + 3); \
  BAR; \
  __builtin_amdgcn_s_setprio(1); \
  acc[0][0] = MF(a0, b0, acc[0][0]); acc[0][1] = MF(a0, b1, acc[0][1]); \
  acc[0][2] = MF(a0, b2, acc[0][2]); acc[0][3] = MF(a0, b3, acc[0][3]); \
  acc[1][0] = MF(a1, b0, acc[1][0]); acc[1][1] = MF(a1, b1, acc[1][1]); \
  acc[1][2] = MF(a1, b2, acc[1][2]); acc[1][3] = MF(a1, b3, acc[1][3]); \
  acc[2][0] = MF(a2, b0, acc[2][0]); acc[2][1] = MF(a2, b1, acc[2][1]); \
  acc[2][2] = MF(a2, b2, acc[2][2]); acc[2][3] = MF(a2, b3, acc[2][3]); \
  acc[3][0] = MF(a3, b0, acc[3][0]); acc[3][1] = MF(a3, b1, acc[3][1]); \
  acc[3][2] = MF(a3, b2, acc[3][2]); acc[3][3] = MF(a3, b3, acc[3][3]); \
  __builtin_amdgcn_s_setprio(0); \
  BAR; \
  a0 = *(const bf16x8*)(LA + sb + aoff + 2048); \
  a1 = *(const bf16x8*)(LA + sb + aoff + 2560); \
  a2 = *(const bf16x8*)(LA + sb + aoff + 3072); \
  a3 = *(const bf16x8*)(LA + sb + aoff + 3584); \
  if (STG) STAGE_B((t) + 3); \
  BAR; \
  __builtin_amdgcn_s_setprio(1); \
  acc[4][0] = MF(a0, b0, acc[4][0]); acc[4][1] = MF(a0, b1, acc[4][1]); \
  acc[4][2] = MF(a0, b2, acc[4][2]); acc[4][3] = MF(a0, b3, acc[4][3]); \
  acc[5][0] = MF(a1, b0, acc[5][0]); acc[5][1] = MF(a1, b1, acc[5][1]); \
  acc[5][2] = MF(a1, b2, acc[5][2]); acc[5][3] = MF(a1, b3, acc[5][3]); \
  acc[6][0] = MF(a2, b0, acc[6][0]); acc[6][1] = MF(a2, b1, acc[6][1]); \
  acc[6][2] = MF(a2, b2, acc[6][2]); acc[6][3] = MF(a2, b3, acc[6][3]); \
  acc[7][0] = MF(a3, b0, acc[7][0]); acc[7][1] = MF(a3, b1, acc[7][1]); \
  acc[7][2] = MF(a3, b2, acc[7][2]); acc[7][3] = MF(a3, b3, acc[7][3]); \
  __builtin_amdgcn_s_setprio(0); \
  VMW; \
  BAR; \
} while (0)

  // main loop: 128 K-tiles; stage tile t+3 while computing t (slot of t-1: reads retired)
  for (int t = 0; t < 125; ++t) { TILE(t, 1, VM8); }
  TILE(125, 0, VM4);
  TILE(126, 0, VM0);
  TILE(127, 0, VMN);

  // epilogue: C = acc + bias   (C/D map: col = l&15, row = (l>>4)*4 + reg)
  const int crow = m0 + (wid >> 2) * 128 + ((l >> 4) << 2);
  const int ccol = n0 + (wid & 3) * 64 + (l & 15);
#pragma unroll
  for (int nf = 0; nf < 4; ++nf) {
    const float bv = Bias[ccol + nf * 16];
#pragma unroll
    for (int f = 0; f < 8; ++f)
#pragma unroll
      for (int rg = 0; rg < 4; ++rg)
        Out[(size_t)(crow + f * 16 + rg) * OUT_F + ccol + nf * 16] = acc[f][nf][rg] + bv;
  }
}

// ---------------- fallback: fused kernel (if ws too small / shape off) ----------------
__global__ __launch_bounds__(256, 2) void nf4_gemm_fused(
    const float* __restrict__ X, const int* __restrict__ Wp,
    const float* __restrict__ Amax, const float* __restrict__ Bias,
    float* __restrict__ Out, int M) {
  __shared__ unsigned short As[128 * 64];
  __shared__ unsigned short Bs[128 * 64];
  __shared__ float lutS[16];

  const int t = threadIdx.x;
  const int l = t & 63;
  const int wid = t >> 6;

  if (t < 16) {
    const float lut[16] = {-1.0f, -0.6961928009986877f, -0.5250730514526367f,
        -0.39491719007492065f, -0.28444138169288635f, -0.18477343022823334f,
        -0.08820830285549164f, 0.0f, 0.07107656449079514f, 0.14263366162776947f,
        0.22430233657360077f, 0.3203405737876892f, 0.4407068192958832f,
        0.5905631184577942f, 0.796090841293335f, 1.0f};
    lutS[t] = lut[t];
  }

  const int ntile = OUT_F / 128;
  const int m0 = (blockIdx.x / ntile) * 128;
  const int n0 = (blockIdx.x % ntile) * 128;

  const int ar = t >> 4;
  const int ac4 = t & 15;
  const int br = t >> 3;
  const int bg = t & 7;
  const int wm = (wid >> 1) * 64;
  const int wn = (wid & 1) * 64;

  f32x4 acc[4][4];
#pragma unroll
  for (int i = 0; i < 4; ++i)
#pragma unroll
    for (int j = 0; j < 4; ++j) acc[i][j] = {0.f, 0.f, 0.f, 0.f};

  __syncthreads();

  for (int k0 = 0; k0 < IN_F; k0 += 64) {
#pragma unroll
    for (int p = 0; p < 8; ++p) {
      const int r = p * 16 + ar;
      const float4 v = *reinterpret_cast<const float4*>(
          X + (size_t)(m0 + r) * IN_F + k0 + ac4 * 4);
      us4 h;
      h[0] = f2bf(v.x); h[1] = f2bf(v.y); h[2] = f2bf(v.z); h[3] = f2bf(v.w);
      const int byte = r * 128 + ((ac4 * 8) ^ ((r & 7) << 4));
      *reinterpret_cast<us4*>(reinterpret_cast<char*>(As) + byte) = h;
    }
#pragma unroll
    for (int p = 0; p < 4; ++p) {
      const int r = p * 32 + br;
      const float amv = Amax[(size_t)(n0 + r) * (IN_F / 64) + (k0 >> 6)];
      const int4 pk = *reinterpret_cast<const int4*>(
          Wp + (size_t)(n0 + r) * (IN_F / 2) + (k0 >> 1) + bg * 4);
      us8 h;
      {
        int c;
        c = pk.x & 255; h[0] = f2bf(lutS[c & 15] * amv); h[1] = f2bf(lutS[c >> 4] * amv);
        c = pk.y & 255; h[2] = f2bf(lutS[c & 15] * amv); h[3] = f2bf(lutS[c >> 4] * amv);
        c = pk.z & 255; h[4] = f2bf(lutS[c & 15] * amv); h[5] = f2bf(lutS[c >> 4] * amv);
        c = pk.w & 255; h[6] = f2bf(lutS[c & 15] * amv); h[7] = f2bf(lutS[c >> 4] * amv);
      }
      const int byte = r * 128 + ((bg * 16) ^ ((r & 7) << 4));
      *reinterpret_cast<us8*>(reinterpret_cast<char*>(Bs) + byte) = h;
    }
    __syncthreads();

#pragma unroll
    for (int kk = 0; kk < 64; kk += 32) {
      bf16x8 af[4], bfv[4];
      const int kb = (kk + ((l >> 4) << 3)) * 2;
#pragma unroll
      for (int i = 0; i < 4; ++i) {
        const int row = wm + i * 16 + (l & 15);
        af[i] = *reinterpret_cast<const bf16x8*>(
            reinterpret_cast<const char*>(As) + row * 128 + (kb ^ ((row & 7) << 4)));
      }
#pragma unroll
      for (int j = 0; j < 4; ++j) {
        const int row = wn + j * 16 + (l & 15);
        bfv[j] = *reinterpret_cast<const bf16x8*>(
            reinterpret_cast<const char*>(Bs) + row * 128 + (kb ^ ((row & 7) << 4)));
      }
#pragma unroll
      for (int i = 0; i < 4; ++i)
#pragma unroll
        for (int j = 0; j < 4; ++j)
          acc[i][j] = __builtin_amdgcn_mfma_f32_16x16x32_bf16(af[i], bfv[j], acc[i][j], 0, 0, 0);
    }
    __syncthreads();
  }

  const int crow0 = m0 + wm + ((l >> 4) << 2);
  const int ccol0 = n0 + wn + (l & 15);
#pragma unroll
  for (int j = 0; j < 4; ++j) {
    const float bv = Bias[ccol0 + j * 16];
#pragma unroll
    for (int i = 0; i < 4; ++i)
#pragma unroll
      for (int rg = 0; rg < 4; ++rg)
        Out[(size_t)(crow0 + i * 16 + rg) * OUT_F + ccol0 + j * 16] = acc[i][j][rg] + bv;
  }
}

extern "C" void kernel_launch(void* const* d_in, const int* in_sizes, int n_in,
                              void* d_out, int out_size, void* d_ws, size_t ws_size,
                              hipStream_t stream) {
  const float* X = (const float*)d_in[0];
  const int* Wp = (const int*)d_in[1];
  const float* Amax = (const float*)d_in[2];
  const float* Bias = (const float*)d_in[3];
  float* Out = (float*)d_out;

  const int M = in_sizes[0] / IN_F;                       // 8192
  const size_t needX = (size_t)M * IN_F * 2;
  const size_t needW = (size_t)OUT_F * IN_F * 2;
  const int grid256 = (M / 256) * (OUT_F / 256);          // 32*43 = 1376

  if (ws_size >= needX + needW && (M % 256) == 0 && (grid256 & 7) == 0) {
    unsigned short* Xb = (unsigned short*)d_ws;
    unsigned short* Wb = Xb + (size_t)M * IN_F;
    (void)hipFuncSetAttribute(reinterpret_cast<const void*>(gemm256),
                              hipFuncAttributeMaxDynamicSharedMemorySize, 131072);
    cvt_x<<<2048, 256, 0, stream>>>(X, Xb, M * (IN_F / 8));
    dequant_w<<<2048, 256, 0, stream>>>(Wp, Amax, Wb, OUT_F * (IN_F / 8));
    gemm256<<<grid256, 512, 131072, stream>>>(Xb, Wb, Bias, Out, M);
  } else {
    const int grid = (M / 128) * (OUT_F / 128);
    nf4_gemm_fused<<<grid, 256, 0, stream>>>(X, Wp, Amax, Bias, Out, M);
  }
}

// Round 6
// 850.425 us; speedup vs baseline: 1.1496x; 1.0538x over previous
//
#include <hip/hip_runtime.h>

#define IN_F 4096
#define OUT_F 11008

typedef __attribute__((ext_vector_type(8))) short bf16x8;   // 8 bf16 (4 VGPR) MFMA operand
typedef __attribute__((ext_vector_type(4))) float f32x4;
typedef __attribute__((ext_vector_type(4))) unsigned short us4;
typedef __attribute__((ext_vector_type(8))) unsigned short us8;

__device__ __forceinline__ unsigned short f2bf(float f) {
  unsigned int u = __float_as_uint(f);
  u += 0x7FFFu + ((u >> 16) & 1u);   // RNE
  return (unsigned short)(u >> 16);
}

// ---------------- prepass 1: X fp32 -> bf16 ----------------
__global__ __launch_bounds__(256) void cvt_x(const float* __restrict__ X,
                                             unsigned short* __restrict__ Xb, int n8) {
  for (int i = blockIdx.x * blockDim.x + threadIdx.x; i < n8;
       i += gridDim.x * blockDim.x) {
    const float4 a = reinterpret_cast<const float4*>(X)[2 * i];
    const float4 b = reinterpret_cast<const float4*>(X)[2 * i + 1];
    us8 h;
    h[0] = f2bf(a.x); h[1] = f2bf(a.y); h[2] = f2bf(a.z); h[3] = f2bf(a.w);
    h[4] = f2bf(b.x); h[5] = f2bf(b.y); h[6] = f2bf(b.z); h[7] = f2bf(b.w);
    reinterpret_cast<us8*>(Xb)[i] = h;
  }
}

// ---------------- prepass 2: W nf4 packed -> bf16 (dequant once) ----------------
__global__ __launch_bounds__(256) void dequant_w(const int* __restrict__ Wp,
                                                 const float* __restrict__ Amax,
                                                 unsigned short* __restrict__ Wb, int n4) {
  __shared__ float lutS[16];
  if (threadIdx.x < 16) {
    const float lut[16] = {-1.0f, -0.6961928009986877f, -0.5250730514526367f,
        -0.39491719007492065f, -0.28444138169288635f, -0.18477343022823334f,
        -0.08820830285549164f, 0.0f, 0.07107656449079514f, 0.14263366162776947f,
        0.22430233657360077f, 0.3203405737876892f, 0.4407068192958832f,
        0.5905631184577942f, 0.796090841293335f, 1.0f};
    lutS[threadIdx.x] = lut[threadIdx.x];
  }
  __syncthreads();
  for (int i = blockIdx.x * blockDim.x + threadIdx.x; i < n4;
       i += gridDim.x * blockDim.x) {
    const int j = i * 4;
    const int row = j >> 11;
    const int coli = j & 2047;
    const float am = Amax[row * (IN_F / 64) + (coli >> 5)];
    const int4 pk = reinterpret_cast<const int4*>(Wp)[i];
    us8 h; int c;
    c = pk.x & 255; h[0] = f2bf(lutS[c & 15] * am); h[1] = f2bf(lutS[c >> 4] * am);
    c = pk.y & 255; h[2] = f2bf(lutS[c & 15] * am); h[3] = f2bf(lutS[c >> 4] * am);
    c = pk.z & 255; h[4] = f2bf(lutS[c & 15] * am); h[5] = f2bf(lutS[c >> 4] * am);
    c = pk.w & 255; h[6] = f2bf(lutS[c & 15] * am); h[7] = f2bf(lutS[c >> 4] * am);
    reinterpret_cast<us8*>(Wb)[i] = h;
  }
}

// ---------------- main GEMM: 256x256, BK=32 ring-4, 1 barrier/tile ----------------
#define MF(a, b, c) __builtin_amdgcn_mfma_f32_16x16x32_bf16(a, b, c, 0, 0, 0)
#define GLDS(src, dst) __builtin_amdgcn_global_load_lds( \
    (const __attribute__((address_space(1))) void*)(src), \
    (__attribute__((address_space(3))) void*)(dst), 16, 0, 0)
#define FENCE asm volatile("" ::: "memory")
#define BAR do { FENCE; __builtin_amdgcn_s_barrier(); FENCE; } while (0)
#define VM8 asm volatile("s_waitcnt vmcnt(8)" ::: "memory")
#define VM4 asm volatile("s_waitcnt vmcnt(4)" ::: "memory")
#define VM0 asm volatile("s_waitcnt vmcnt(0)" ::: "memory")

__global__ __launch_bounds__(512, 2) void gemm256(
    const unsigned short* __restrict__ A,   // (M, K) bf16
    const unsigned short* __restrict__ B,   // (N, K) bf16
    const float* __restrict__ Bias, float* __restrict__ Out, int M) {
  extern __shared__ unsigned short sm[];    // 128 KiB: 4 A-slots + 4 B-slots (16 KiB each)
  unsigned short* LA = sm;
  unsigned short* LB = sm + 32768;

  const int tid = threadIdx.x;
  const int l = tid & 63;
  const int wid = tid >> 6;

  const int Mb = M / 256;                   // 32
  const int Nb = OUT_F / 256;               // 43
  const int cpx = (Mb * Nb) >> 3;           // 172
  const int bid = (blockIdx.x & 7) * cpx + (blockIdx.x >> 3);
  const int m0 = (bid % Mb) * 256;          // m-fast: B-panel L2-resident per XCD
  const int n0 = (bid / Mb) * 256;

  // --- ds_read lane constants (paired-row layout: phys row = 2 logical rows, 128 B) ---
  // logical (R, kchunk) stored at phys (R>>1, ((R&1)*4 + kchunk) ^ (physrow&7))
  const int rh = (l & 15) >> 1;
  const int cph = (((l & 1) << 2) + (l >> 4)) ^ rh;       // phys 16B chunk, lane const
  const int aoff = (((wid >> 2) * 64) + rh) * 64 + cph * 8;   // elements
  const int boff = (((wid & 3) * 32) + rh) * 64 + cph * 8;

  // --- stage lane constants (LDS dest linear: wave base + lane*16B) ---
  const int cc = (l & 7) ^ (l >> 3);            // content chunk at this lane's dest
  const int R0 = 2 * (wid * 16 + (l >> 3)) + (cc >> 2);   // q=0 logical row within tile
  const long chb = (long)(cc & 3) * 16;                    // source k-chunk bytes
  const char* pA0 = (const char*)A + ((size_t)(m0 + R0) * IN_F) * 2 + chb;
  const char* pA1 = (const char*)A + ((size_t)(m0 + R0 + 16) * IN_F) * 2 + chb;
  const char* pB0 = (const char*)B + ((size_t)(n0 + R0) * IN_F) * 2 + chb;
  const char* pB1 = (const char*)B + ((size_t)(n0 + R0 + 16) * IN_F) * 2 + chb;
  const int dq0 = wid * 1024;                  // elements within slot
  const int dq1 = wid * 1024 + 512;

#define STAGE_A(tt) do { const int s_ = ((tt) & 3) * 8192; const size_t ko_ = (size_t)(tt) * 64; \
    GLDS(pA0 + ko_, LA + s_ + dq0); GLDS(pA1 + ko_, LA + s_ + dq1); } while (0)
#define STAGE_B(tt) do { const int s_ = ((tt) & 3) * 8192; const size_t ko_ = (size_t)(tt) * 64; \
    GLDS(pB0 + ko_, LB + s_ + dq0); GLDS(pB1 + ko_, LB + s_ + dq1); } while (0)

  f32x4 acc[8][4];
#pragma unroll
  for (int i = 0; i < 8; ++i)
#pragma unroll
    for (int j = 0; j < 4; ++j) acc[i][j] = {0.f, 0.f, 0.f, 0.f};

  // prologue: stage tiles 0,1,2 (12 loads in flight). Sync happens inside TILE(0):
  // VM8 retires this wave's tile-0 loads, BAR makes that true for ALL waves.
  STAGE_A(0); STAGE_B(0); STAGE_A(1); STAGE_B(1); STAGE_A(2); STAGE_B(2);

  // TILE(t): VMW | BAR | reads(t) | mfma(lo) | STAGE(t+3) | mfma(hi)
  // Data-ready: each wave's VMW (before BAR@t) retires ITS tile-t loads; reads are
  //   after BAR@t => all waves' loads landed.                               [race-free]
  // WAR: STAGE(t+3) hits slot (t-1)&3, issued after BAR@t; every wave's reads of that
  //   slot were lgkm-consumed by mfma(t-1) before it reached BAR@t.         [race-free]
#define TILE(t, STG, VMW) do { \
  VMW; \
  BAR; \
  const int sb = ((t) & 3) * 8192; \
  bf16x8 a0, a1, a2, a3, a4, a5, a6, a7, b0, b1, b2, b3; \
  a0 = *(const bf16x8*)(LA + sb + aoff); \
  a1 = *(const bf16x8*)(LA + sb + aoff + 512); \
  a2 = *(const bf16x8*)(LA + sb + aoff + 1024); \
  a3 = *(const bf16x8*)(LA + sb + aoff + 1536); \
  b0 = *(const bf16x8*)(LB + sb + boff); \
  b1 = *(const bf16x8*)(LB + sb + boff + 512); \
  b2 = *(const bf16x8*)(LB + sb + boff + 1024); \
  b3 = *(const bf16x8*)(LB + sb + boff + 1536); \
  a4 = *(const bf16x8*)(LA + sb + aoff + 2048); \
  a5 = *(const bf16x8*)(LA + sb + aoff + 2560); \
  a6 = *(const bf16x8*)(LA + sb + aoff + 3072); \
  a7 = *(const bf16x8*)(LA + sb + aoff + 3584); \
  __builtin_amdgcn_s_setprio(1); \
  acc[0][0] = MF(a0, b0, acc[0][0]); acc[0][1] = MF(a0, b1, acc[0][1]); \
  acc[0][2] = MF(a0, b2, acc[0][2]); acc[0][3] = MF(a0, b3, acc[0][3]); \
  acc[1][0] = MF(a1, b0, acc[1][0]); acc[1][1] = MF(a1, b1, acc[1][1]); \
  acc[1][2] = MF(a1, b2, acc[1][2]); acc[1][3] = MF(a1, b3, acc[1][3]); \
  acc[2][0] = MF(a2, b0, acc[2][0]); acc[2][1] = MF(a2, b1, acc[2][1]); \
  acc[2][2] = MF(a2, b2, acc[2][2]); acc[2][3] = MF(a2, b3, acc[2][3]); \
  acc[3][0] = MF(a3, b0, acc[3][0]); acc[3][1] = MF(a3, b1, acc[3][1]); \
  acc[3][2] = MF(a3, b2, acc[3][2]); acc[3][3] = MF(a3, b3, acc[3][3]); \
  __builtin_amdgcn_s_setprio(0); \
  if (STG) { STAGE_A((t) + 3); STAGE_B((t) + 3); } \
  __builtin_amdgcn_s_setprio(1); \
  acc[4][0] = MF(a4, b0, acc[4][0]); acc[4][1] = MF(a4, b1, acc[4][1]); \
  acc[4][2] = MF(a4, b2, acc[4][2]); acc[4][3] = MF(a4, b3, acc[4][3]); \
  acc[5][0] = MF(a5, b0, acc[5][0]); acc[5][1] = MF(a5, b1, acc[5][1]); \
  acc[5][2] = MF(a5, b2, acc[5][2]); acc[5][3] = MF(a5, b3, acc[5][3]); \
  acc[6][0] = MF(a6, b0, acc[6][0]); acc[6][1] = MF(a6, b1, acc[6][1]); \
  acc[6][2] = MF(a6, b2, acc[6][2]); acc[6][3] = MF(a6, b3, acc[6][3]); \
  acc[7][0] = MF(a7, b0, acc[7][0]); acc[7][1] = MF(a7, b1, acc[7][1]); \
  acc[7][2] = MF(a7, b2, acc[7][2]); acc[7][3] = MF(a7, b3, acc[7][3]); \
  __builtin_amdgcn_s_setprio(0); \
} while (0)

  // main loop: 128 K-tiles; stage t+3 while computing t; last stage at t=124.
  for (int t = 0; t < 125; ++t) { TILE(t, 1, VM8); }
  TILE(125, 0, VM8);   // outstanding 125,126,127=12 -> retire 125
  TILE(126, 0, VM4);   // outstanding 126,127=8     -> retire 126
  TILE(127, 0, VM0);   // outstanding 127=4         -> retire 127

  // epilogue: C = acc + bias   (C/D map: col = l&15, row = (l>>4)*4 + reg)
  const int crow = m0 + (wid >> 2) * 128 + ((l >> 4) << 2);
  const int ccol = n0 + (wid & 3) * 64 + (l & 15);
#pragma unroll
  for (int nf = 0; nf < 4; ++nf) {
    const float bv = Bias[ccol + nf * 16];
#pragma unroll
    for (int f = 0; f < 8; ++f)
#pragma unroll
      for (int rg = 0; rg < 4; ++rg)
        Out[(size_t)(crow + f * 16 + rg) * OUT_F + ccol + nf * 16] = acc[f][nf][rg] + bv;
  }
}

// ---------------- fallback: fused kernel (if ws too small / shape off) ----------------
__global__ __launch_bounds__(256, 2) void nf4_gemm_fused(
    const float* __restrict__ X, const int* __restrict__ Wp,
    const float* __restrict__ Amax, const float* __restrict__ Bias,
    float* __restrict__ Out, int M) {
  __shared__ unsigned short As[128 * 64];
  __shared__ unsigned short Bs[128 * 64];
  __shared__ float lutS[16];

  const int t = threadIdx.x;
  const int l = t & 63;
  const int wid = t >> 6;

  if (t < 16) {
    const float lut[16] = {-1.0f, -0.6961928009986877f, -0.5250730514526367f,
        -0.39491719007492065f, -0.28444138169288635f, -0.18477343022823334f,
        -0.08820830285549164f, 0.0f, 0.07107656449079514f, 0.14263366162776947f,
        0.22430233657360077f, 0.3203405737876892f, 0.4407068192958832f,
        0.5905631184577942f, 0.796090841293335f, 1.0f};
    lutS[t] = lut[t];
  }

  const int ntile = OUT_F / 128;
  const int m0 = (blockIdx.x / ntile) * 128;
  const int n0 = (blockIdx.x % ntile) * 128;

  const int ar = t >> 4;
  const int ac4 = t & 15;
  const int br = t >> 3;
  const int bg = t & 7;
  const int wm = (wid >> 1) * 64;
  const int wn = (wid & 1) * 64;

  f32x4 acc[4][4];
#pragma unroll
  for (int i = 0; i < 4; ++i)
#pragma unroll
    for (int j = 0; j < 4; ++j) acc[i][j] = {0.f, 0.f, 0.f, 0.f};

  __syncthreads();

  for (int k0 = 0; k0 < IN_F; k0 += 64) {
#pragma unroll
    for (int p = 0; p < 8; ++p) {
      const int r = p * 16 + ar;
      const float4 v = *reinterpret_cast<const float4*>(
          X + (size_t)(m0 + r) * IN_F + k0 + ac4 * 4);
      us4 h;
      h[0] = f2bf(v.x); h[1] = f2bf(v.y); h[2] = f2bf(v.z); h[3] = f2bf(v.w);
      const int byte = r * 128 + ((ac4 * 8) ^ ((r & 7) << 4));
      *reinterpret_cast<us4*>(reinterpret_cast<char*>(As) + byte) = h;
    }
#pragma unroll
    for (int p = 0; p < 4; ++p) {
      const int r = p * 32 + br;
      const float amv = Amax[(size_t)(n0 + r) * (IN_F / 64) + (k0 >> 6)];
      const int4 pk = *reinterpret_cast<const int4*>(
          Wp + (size_t)(n0 + r) * (IN_F / 2) + (k0 >> 1) + bg * 4);
      us8 h;
      {
        int c;
        c = pk.x & 255; h[0] = f2bf(lutS[c & 15] * amv); h[1] = f2bf(lutS[c >> 4] * amv);
        c = pk.y & 255; h[2] = f2bf(lutS[c & 15] * amv); h[3] = f2bf(lutS[c >> 4] * amv);
        c = pk.z & 255; h[4] = f2bf(lutS[c & 15] * amv); h[5] = f2bf(lutS[c >> 4] * amv);
        c = pk.w & 255; h[6] = f2bf(lutS[c & 15] * amv); h[7] = f2bf(lutS[c >> 4] * amv);
      }
      const int byte = r * 128 + ((bg * 16) ^ ((r & 7) << 4));
      *reinterpret_cast<us8*>(reinterpret_cast<char*>(Bs) + byte) = h;
    }
    __syncthreads();

#pragma unroll
    for (int kk = 0; kk < 64; kk += 32) {
      bf16x8 af[4], bfv[4];
      const int kb = (kk + ((l >> 4) << 3)) * 2;
#pragma unroll
      for (int i = 0; i < 4; ++i) {
        const int row = wm + i * 16 + (l & 15);
        af[i] = *reinterpret_cast<const bf16x8*>(
            reinterpret_cast<const char*>(As) + row * 128 + (kb ^ ((row & 7) << 4)));
      }
#pragma unroll
      for (int j = 0; j < 4; ++j) {
        const int row = wn + j * 16 + (l & 15);
        bfv[j] = *reinterpret_cast<const bf16x8*>(
            reinterpret_cast<const char*>(Bs) + row * 128 + (kb ^ ((row & 7) << 4)));
      }
#pragma unroll
      for (int i = 0; i < 4; ++i)
#pragma unroll
        for (int j = 0; j < 4; ++j)
          acc[i][j] = __builtin_amdgcn_mfma_f32_16x16x32_bf16(af[i], bfv[j], acc[i][j], 0, 0, 0);
    }
    __syncthreads();
  }

  const int crow0 = m0 + wm + ((l >> 4) << 2);
  const int ccol0 = n0 + wn + (l & 15);
#pragma unroll
  for (int j = 0; j < 4; ++j) {
    const float bv = Bias[ccol0 + j * 16];
#pragma unroll
    for (int i = 0; i < 4; ++i)
#pragma unroll
      for (int rg = 0; rg < 4; ++rg)
        Out[(size_t)(crow0 + i * 16 + rg) * OUT_F + ccol0 + j * 16] = acc[i][j][rg] + bv;
  }
}

extern "C" void kernel_launch(void* const* d_in, const int* in_sizes, int n_in,
                              void* d_out, int out_size, void* d_ws, size_t ws_size,
                              hipStream_t stream) {
  const float* X = (const float*)d_in[0];
  const int* Wp = (const int*)d_in[1];
  const float* Amax = (const float*)d_in[2];
  const float* Bias = (const float*)d_in[3];
  float* Out = (float*)d_out;

  const int M = in_sizes[0] / IN_F;                       // 8192
  const size_t needX = (size_t)M * IN_F * 2;
  const size_t needW = (size_t)OUT_F * IN_F * 2;
  const int grid256 = (M / 256) * (OUT_F / 256);          // 32*43 = 1376

  if (ws_size >= needX + needW && (M % 256) == 0 && (grid256 & 7) == 0) {
    unsigned short* Xb = (unsigned short*)d_ws;
    unsigned short* Wb = Xb + (size_t)M * IN_F;
    (void)hipFuncSetAttribute(reinterpret_cast<const void*>(gemm256),
                              hipFuncAttributeMaxDynamicSharedMemorySize, 131072);
    cvt_x<<<2048, 256, 0, stream>>>(X, Xb, M * (IN_F / 8));
    dequant_w<<<2048, 256, 0, stream>>>(Wp, Amax, Wb, OUT_F * (IN_F / 8));
    gemm256<<<grid256, 512, 131072, stream>>>(Xb, Wb, Bias, Out, M);
  } else {
    const int grid = (M / 128) * (OUT_F / 128);
    nf4_gemm_fused<<<grid, 256, 0, stream>>>(X, Wp, Amax, Bias, Out, M);
  }
}